// Round 10
// baseline (42.797 us; speedup 1.0000x reference)
//
#include <hip/hip_runtime.h>
#include <math.h>

#define BB 2
#define NN 4096
#define CC 33
#define TILE 64
#define NTILES (NN / TILE)            // 64
#define NPB 1056                      // sum over ti of (32 - ti/2) 64x128 blocks
#define PAIRBLK (BB * NPB)            // 2112
#define NDIAG (BB * NTILES)           // 128 diagonal-tile blocks (own CE/focal/match)
#define RPF 36                        // LDS row pitch in dwords (144 B, 16B-aligned)

typedef __attribute__((ext_vector_type(8))) short frag_ab;   // 8 bf16 (4 VGPRs)
typedef __attribute__((ext_vector_type(4))) float f32x4;     // 4 fp32 accum

__device__ __forceinline__ float fast_sqrt(float x) {
    return __builtin_amdgcn_sqrtf(x);                        // v_sqrt_f32, ~2 ULP
}
__device__ __forceinline__ unsigned f2bf(float x) {          // RNE, x in [0,1]
    unsigned u = __float_as_uint(x);
    return (u + 0x7FFFu + ((u >> 16) & 1u)) >> 16;
}
__device__ __forceinline__ float bf2f(unsigned b) {
    return __uint_as_float(b << 16);
}

// ONE kernel: per-block private softmax (redundant, cheap) + 64x128 Gram tile
// via bf16 MFMA + fence-free fused finalize (R8 protocol: agent atomics + sc1,
// vmcnt(0) ordering, master counter; all partials via atomic STORES so no
// zero-init needed except master, reset by a captured 4-byte memset).
__global__ __launch_bounds__(256) void fused_kernel(
    const float* __restrict__ pred, const int* __restrict__ targets,
    const int* __restrict__ pred_choice,
    float* __restrict__ part_pair, float* __restrict__ part_ce,
    float* __restrict__ part_fo, int* __restrict__ part_mt,
    unsigned* __restrict__ master, float* __restrict__ out)
{
    __shared__ __align__(16) float sraw[192 * RPF];   // 27.6 KB: f32 rows -> bf16 in place
    __shared__ float ssq[192];
    __shared__ float red[4];
    __shared__ int lastFlag;
    __shared__ double lds_ce[4], lds_fo[4], lds_pr[4];
    __shared__ int lds_mt[4];

    int bid = blockIdx.x;
    int b = bid / NPB;
    int t0 = bid % NPB;

    // decode (ti, tjA): row ti has 32 - ti/2 j-pair blocks
    int ti = 0, rem = t0;
    while (rem >= 32 - (ti >> 1)) { rem -= 32 - (ti >> 1); ++ti; }
    int tjA = ti + 2 * rem;
    bool hasB = (tjA + 1 < NTILES);
    bool diagA = (tjA == ti);
    int i0 = ti * TILE, j0A = tjA * TILE;
    int jcnt = hasB ? 128 : 64;

    // ---- phase 1: stage raw f32 rows. region rows 0..63 = i-tile,
    //      64..64+jcnt-1 = j-tiles (both source chunks contiguous, 16B-aligned)
    {
        const float4* srcI = (const float4*)(pred + ((size_t)b * NN + i0) * CC);
        const float4* srcJ = (const float4*)(pred + ((size_t)b * NN + j0A) * CC);
        int jf4 = (jcnt * CC) / 4;                    // 528 or 1056
        int tot = 528 + jf4;
        for (int k = threadIdx.x; k < tot; k += 256) {
            int isJ = (k >= 528);
            int kk = isJ ? k - 528 : k;
            float4 val = isJ ? srcJ[kk] : srcI[kk];
            int rowoff = isJ ? 64 : 0;
            int flat = kk * 4;
            float vv[4] = {val.x, val.y, val.z, val.w};
            #pragma unroll
            for (int e = 0; e < 4; e++) {
                int f = flat + e;
                int r = f / CC;
                int c = f - r * CC;
                sraw[(rowoff + r) * RPF + c] = vv[e];
            }
        }
    }
    __syncthreads();

    // ---- phase 2: thread t owns region row t: serial softmax, in-place bf16
    float ce = 0.f, fo = 0.f; int mt = 0;
    {
        int t = threadIdx.x;
        if (t < 64 + jcnt) {
            int base = t * RPF;
            float v[33];
            #pragma unroll
            for (int c = 0; c < 33; c++) v[c] = sraw[base + c];
            float m = v[0];
            #pragma unroll
            for (int c = 1; c < 33; c++) m = fmaxf(m, v[c]);
            float s = 0.f;
            #pragma unroll
            for (int c = 0; c < 33; c++) { v[c] = __expf(v[c] - m); s += v[c]; }
            if (diagA && t < 64) {                    // CE/focal/match: once per row
                int g = b * NN + i0 + t;
                int tg = targets[g];
                float vt = sraw[base + tg];           // raw row still intact here
                float logpt = (vt - m) - __logf(s);
                ce = -logpt;
                float pt = __expf(vt - m) / s;
                float om = 1.f - pt;
                fo = om * om;
                mt = (tg == pred_choice[g]) ? 1 : 0;
            }
            float inv = 1.f / s;
            unsigned d[17];
            float q = 0.f;
            #pragma unroll
            for (int k = 0; k < 16; k++) {
                unsigned lo = f2bf(v[2 * k] * inv);
                unsigned hi = f2bf(v[2 * k + 1] * inv);
                float fl = bf2f(lo), fh = bf2f(hi);
                q += fl * fl + fh * fh;               // sqn in ROUNDED space
                d[k] = lo | (hi << 16);
            }
            {
                unsigned lo = f2bf(v[32] * inv);
                float fl = bf2f(lo);
                q += fl * fl;
                d[16] = lo;                           // hi half 0
            }
            unsigned* dd = (unsigned*)sraw + base;    // overwrite own row only
            #pragma unroll
            for (int k = 0; k < 17; k++) dd[k] = d[k];
            ssq[t] = q;
        }
    }
    __syncthreads();

    // ---- phase 3: MFMA Gram + distance epilogue (bf16 rows at ushort pitch 72)
    int l = threadIdx.x & 63, w = threadIdx.x >> 6;
    int col = l & 15, kc = l >> 4;
    const unsigned short* sus = (const unsigned short*)sraw;

    frag_ab afr = *(const frag_ab*)&sus[(16 * w + col) * 72 + kc * 8];
    float qi[4], c32a[4];
    #pragma unroll
    for (int r = 0; r < 4; r++) {
        int ir = 16 * w + kc * 4 + r;
        qi[r] = ssq[ir];
        c32a[r] = bf2f(sus[ir * 72 + 32]);
    }
    int gi0 = i0 + 16 * w + kc * 4;

    float ssum = 0.f;
    #pragma unroll
    for (int jt = 0; jt < 2; jt++) {
        if (jt == 1 && !hasB) break;                  // block-uniform
        int rbase = 64 + jt * 64;
        int j0 = (tjA + jt) * TILE;
        bool dg = (jt == 0) && diagA;
        #pragma unroll
        for (int n = 0; n < 4; n++) {
            int jr = rbase + 16 * n + col;
            frag_ab bfr = *(const frag_ab*)&sus[jr * 72 + kc * 8];
            f32x4 acc = {0.f, 0.f, 0.f, 0.f};
            acc = __builtin_amdgcn_mfma_f32_16x16x32_bf16(afr, bfr, acc, 0, 0, 0);
            float c32b = bf2f(sus[jr * 72 + 32]);
            float qj = ssq[jr];
            int gj = j0 + 16 * n + col;
            #pragma unroll
            for (int r = 0; r < 4; r++) {
                float g  = fmaf(c32a[r], c32b, acc[r]);
                float d2 = fmaf(-2.f, g, qi[r] + qj);
                float dd = fast_sqrt(fmaxf(d2, 0.f));
                ssum += (!dg || gj > gi0 + r) ? dd : 0.f;
            }
        }
    }

    // ---- phase 4: reduce + fence-free completion protocol
    #pragma unroll
    for (int off = 32; off; off >>= 1) ssum += __shfl_xor(ssum, off);
    if (l == 0) red[w] = ssum;
    if (w == 0) {                                     // wave 0 holds all ce/fo/mt
        #pragma unroll
        for (int off = 32; off; off >>= 1) {
            ce += __shfl_xor(ce, off);
            fo += __shfl_xor(fo, off);
            mt += __shfl_xor(mt, off);
        }
    }
    __syncthreads();
    if (threadIdx.x == 0) {
        float blockSum = red[0] + red[1] + red[2] + red[3];
        __hip_atomic_store(&part_pair[bid], blockSum,
                           __ATOMIC_RELAXED, __HIP_MEMORY_SCOPE_AGENT);
        if (diagA) {
            int did = b * NTILES + ti;
            __hip_atomic_store(&part_ce[did], ce, __ATOMIC_RELAXED, __HIP_MEMORY_SCOPE_AGENT);
            __hip_atomic_store(&part_fo[did], fo, __ATOMIC_RELAXED, __HIP_MEMORY_SCOPE_AGENT);
            __hip_atomic_store(&part_mt[did], mt, __ATOMIC_RELAXED, __HIP_MEMORY_SCOPE_AGENT);
        }
        asm volatile("s_waitcnt vmcnt(0)" ::: "memory");   // stores visible pre-count
        unsigned o = __hip_atomic_fetch_add(master, 1u,
                                            __ATOMIC_RELAXED, __HIP_MEMORY_SCOPE_AGENT);
        lastFlag = (o == PAIRBLK - 1);
    }
    __syncthreads();
    if (!lastFlag) return;

    // ---- winner-only finalize (partials coherent via agent atomics) ----
    double dce = 0.0, dfo = 0.0, dpr = 0.0;
    int dmt = 0;
    for (int i = threadIdx.x; i < PAIRBLK; i += 256)
        dpr += (double)__hip_atomic_load(&part_pair[i],
                                         __ATOMIC_RELAXED, __HIP_MEMORY_SCOPE_AGENT);
    for (int i = threadIdx.x; i < NDIAG; i += 256) {
        dce += (double)__hip_atomic_load(&part_ce[i],
                                         __ATOMIC_RELAXED, __HIP_MEMORY_SCOPE_AGENT);
        dfo += (double)__hip_atomic_load(&part_fo[i],
                                         __ATOMIC_RELAXED, __HIP_MEMORY_SCOPE_AGENT);
        dmt += __hip_atomic_load(&part_mt[i],
                                 __ATOMIC_RELAXED, __HIP_MEMORY_SCOPE_AGENT);
    }
    #pragma unroll
    for (int off = 32; off; off >>= 1) {
        dce += __shfl_xor(dce, off);
        dfo += __shfl_xor(dfo, off);
        dpr += __shfl_xor(dpr, off);
        dmt += __shfl_xor(dmt, off);
    }
    if (l == 0) { lds_ce[w] = dce; lds_fo[w] = dfo; lds_pr[w] = dpr; lds_mt[w] = dmt; }
    __syncthreads();
    if (threadIdx.x == 0) {
        double tce = lds_ce[0] + lds_ce[1] + lds_ce[2] + lds_ce[3];
        double tfo = lds_fo[0] + lds_fo[1] + lds_fo[2] + lds_fo[3];
        double tpr = lds_pr[0] + lds_pr[1] + lds_pr[2] + lds_pr[3];
        int    tmt = lds_mt[0] + lds_mt[1] + lds_mt[2] + lds_mt[3];

        double BN = (double)(BB * NN);
        double loss = (tce / BN) * (tfo / BN);
        double dice = 1.0 - 2.0 * ((double)tmt + 1.0) / (2.0 * BN + 1.0);
        double S = 2.0 * tpr;                    // full matrix sum (diag = 0)
        double mean_pred = S / (BN * (double)NN);
        double dml = 0.05 * log(0.05) - 0.05 * mean_pred;
        out[0] = (float)(loss + dice + dml);
    }
}

extern "C" void kernel_launch(void* const* d_in, const int* in_sizes, int n_in,
                              void* d_out, int out_size, void* d_ws, size_t ws_size,
                              hipStream_t stream)
{
    const float* pred        = (const float*)d_in[0];
    // d_in[1] = y_ohe: unused — the double-where provably collapses dis_map to 0.05
    const int*   targets     = (const int*)d_in[2];
    const int*   pred_choice = (const int*)d_in[3];

    char* ws = (char*)d_ws;
    size_t off = 0;
    float* part_pair = (float*)ws;                           // PAIRBLK f32 (atomic-stored)
    off += (size_t)PAIRBLK * sizeof(float);
    float* part_ce = (float*)(ws + off);                     // NDIAG f32
    off += (size_t)NDIAG * sizeof(float);
    float* part_fo = (float*)(ws + off);                     // NDIAG f32
    off += (size_t)NDIAG * sizeof(float);
    int* part_mt = (int*)(ws + off);                         // NDIAG i32
    off += (size_t)NDIAG * sizeof(int);
    off = (off + 127) & ~(size_t)127;
    unsigned* master = (unsigned*)(ws + off);                // completion counter
    off += sizeof(unsigned);

    hipMemsetAsync(master, 0, sizeof(unsigned), stream);     // reset each replay
    fused_kernel<<<PAIRBLK, 256, 0, stream>>>(pred, targets, pred_choice,
                                              part_pair, part_ce, part_fo,
                                              part_mt, master, (float*)d_out);
}

// Round 11
// 23.182 us; speedup vs baseline: 1.8462x; 1.8462x over previous
//
#include <hip/hip_runtime.h>
#include <math.h>

#define BB 2
#define NN 4096
#define CC 33
#define RP 40                         // bf16 row pitch in ushorts (80 B, 16B-aligned)
#define TILE 64
#define NTILES (NN / TILE)            // 64
#define NPB 1056                      // 64x128 blocks per batch = sum over ti of (32 - ti/2)
#define ROWBLK ((BB * NN) / 8)        // 1024 row-kernel blocks (8 waves = 8 rows each)
#define PAIRBLK (BB * NPB)            // 2112 pair blocks = 33 per slot x 64 slots
#define NSLOT 64
#define SLOTSTR 32                    // 32 words = 128 B between slots (distinct L2 lines)

typedef __attribute__((ext_vector_type(8))) short frag_ab;   // 8 bf16 (4 VGPRs)
typedef __attribute__((ext_vector_type(4))) float f32x4;     // 4 fp32 accum

__device__ __forceinline__ float fast_sqrt(float x) {
    return __builtin_amdgcn_sqrtf(x);                        // v_sqrt_f32, ~2 ULP
}
__device__ __forceinline__ unsigned short f2bf(float x) {
    unsigned u = __float_as_uint(x);
    return (unsigned short)((u + 0x7FFFu + ((u >> 16) & 1u)) >> 16);  // RNE, x>=0 finite
}
__device__ __forceinline__ float bf2f(unsigned short b) {
    return __uint_as_float(((unsigned)b) << 16);
}

// ---------------- kernel 1: per-row softmax -> bf16 probs + partials --------
// 512 threads = 8 waves = 8 rows/block. Block 0 zeroes the slot region
// (stream-ordered before pair_kernel; re-done every call -> replay safe).
__global__ __launch_bounds__(512) void row_kernel(
    const float* __restrict__ pred, const int* __restrict__ targets,
    const int* __restrict__ pred_choice, unsigned short* __restrict__ p16,
    float* __restrict__ sqn, float2* __restrict__ part_row,
    int* __restrict__ part_match, float* __restrict__ slotf,
    unsigned* __restrict__ subcnt, unsigned* __restrict__ master)
{
    __shared__ float2 lds_cf[8];
    __shared__ int lds_mt[8];

    if (blockIdx.x == 0) {
        for (int i = threadIdx.x; i < NSLOT * SLOTSTR; i += 512) {
            slotf[i] = 0.0f;
            subcnt[i] = 0u;
        }
        if (threadIdx.x == 0) *master = 0u;
    }

    int lane = threadIdx.x & 63;
    int wave = threadIdx.x >> 6;
    int row = blockIdx.x * 8 + wave;

    float v = (lane < CC) ? pred[(size_t)row * CC + lane] : -INFINITY;

    float m = v;
    #pragma unroll
    for (int off = 32; off; off >>= 1) m = fmaxf(m, __shfl_xor(m, off));

    float e = (lane < CC) ? __expf(v - m) : 0.0f;
    float s = e;
    #pragma unroll
    for (int off = 32; off; off >>= 1) s += __shfl_xor(s, off);

    float pv = e / s;                        // 0 for lanes >= 33

    unsigned short pb = f2bf(pv);            // bf16-rounded prob (0 stays 0)
    if (lane < RP) p16[(size_t)row * RP + lane] = pb;

    float pf = bf2f(pb);                     // sqn in ROUNDED space (matches MFMA dots)
    float sq = pf * pf;
    #pragma unroll
    for (int off = 32; off; off >>= 1) sq += __shfl_xor(sq, off);

    int t = targets[row];
    float vt = __shfl(v, t);
    float pt = __shfl(pv, t);
    float logpt = (vt - m) - __logf(s);

    if (lane == 0) {
        sqn[row] = sq;
        float om = 1.0f - pt;
        lds_cf[wave] = make_float2(-logpt, om * om);
        lds_mt[wave] = (t == pred_choice[row]) ? 1 : 0;
    }
    __syncthreads();
    if (threadIdx.x == 0) {
        float ce = 0.0f, fo = 0.0f;
        int mt = 0;
        #pragma unroll
        for (int i = 0; i < 8; i++) {
            ce += lds_cf[i].x; fo += lds_cf[i].y; mt += lds_mt[i];
        }
        part_row[blockIdx.x] = make_float2(ce, fo);
        part_match[blockIdx.x] = mt;
    }
}

// ---------------- kernel 2: 64x128 Gram tiles via bf16 MFMA, fragments read
// DIRECTLY from global p16 (1.3 MB, L2/L1-resident - no LDS staging, no
// barrier, no bank conflicts, no LDS occupancy cap). Fence-free fused
// finalize: R8 slot protocol (64 slot lines x 33 blocks, agent atomics,
// vmcnt(0) ordering, master counter; winner finalizes).
__global__ __launch_bounds__(256) void pair_kernel(
    const unsigned short* __restrict__ p16, const float* __restrict__ sqn,
    const float2* __restrict__ part_row, const int* __restrict__ part_match,
    float* __restrict__ slotf, unsigned* __restrict__ subcnt,
    unsigned* __restrict__ master, float* __restrict__ out)
{
    __shared__ float red[4];
    __shared__ int lastFlag;
    __shared__ double lds_ce[4], lds_fo[4], lds_pr[4];
    __shared__ int lds_mt[4];

    int bid = blockIdx.x;
    int b = bid / NPB;
    int t = bid % NPB;

    // closed-form decode: row-pair p (ti=2p,2p+1) each has (32-p) blocks;
    // cum(p) = p*(65-p). Solve p, then split within the pair.
    int p = (int)(32.5f - fast_sqrt(fmaxf(1056.25f - (float)t, 0.0f)));
    if (p < 0) p = 0;
    if (p > 31) p = 31;
    while (p > 0 && p * (65 - p) > t) --p;
    while (p < 31 && (p + 1) * (64 - p) <= t) ++p;
    int rem = t - p * (65 - p);
    int c0 = 32 - p;
    int ti = 2 * p + (rem >= c0);
    int u = (rem >= c0) ? rem - c0 : rem;
    int tjA = ti + 2 * u;
    bool hasB = (tjA + 1 < NTILES);
    bool diagA = (tjA == ti);

    int i0 = ti * TILE, j0A = tjA * TILE;

    int l = threadIdx.x & 63;
    int w = threadIdx.x >> 6;          // wave = 16-row strip of the i-tile
    int col = l & 15;
    int kc = l >> 4;                   // k-chunk 0..3 (8 bf16 each)

    const unsigned short* pb16 = p16 + (size_t)b * NN * RP;
    const float* sqb = sqn + (size_t)b * NN;

    // A fragment straight from L2: row i0+16w+col, k = kc*8..kc*8+7
    int arow = i0 + 16 * w + col;
    frag_ab afr = *(const frag_ab*)&pb16[(size_t)arow * RP + kc * 8];

    // per-lane row metadata (C layout: col=lane&15, row=(lane>>4)*4+r)
    float qi[4], c32a[4];
    #pragma unroll
    for (int r = 0; r < 4; r++) {
        int ir = i0 + 16 * w + kc * 4 + r;
        qi[r]   = sqb[ir];
        c32a[r] = bf2f(pb16[(size_t)ir * RP + 32]);
    }
    int gi0 = i0 + 16 * w + kc * 4;    // gi = gi0 + r

    float ssum = 0.0f;

    #pragma unroll
    for (int jt = 0; jt < 2; jt++) {
        if (jt == 1 && !hasB) break;                 // block-uniform
        int j0 = j0A + jt * TILE;
        bool dg = (jt == 0) && diagA;

        #pragma unroll
        for (int n = 0; n < 4; n++) {  // 16-col subtiles of this j-tile
            int jrow = j0 + 16 * n + col;
            frag_ab bfr = *(const frag_ab*)&pb16[(size_t)jrow * RP + kc * 8];
            f32x4 acc = {0.0f, 0.0f, 0.0f, 0.0f};
            acc = __builtin_amdgcn_mfma_f32_16x16x32_bf16(afr, bfr, acc, 0, 0, 0);

            float c32b = bf2f(pb16[(size_t)jrow * RP + 32]);
            float qj   = sqb[jrow];
            int   gj   = jrow;

            #pragma unroll
            for (int r = 0; r < 4; r++) {
                float g  = fmaf(c32a[r], c32b, acc[r]);      // + class-32 term
                float d2 = fmaf(-2.0f, g, qi[r] + qj);
                float d  = fast_sqrt(fmaxf(d2, 0.0f));
                ssum += (!dg || gj > gi0 + r) ? d : 0.0f;    // strict upper on diag
            }
        }
    }

    #pragma unroll
    for (int off = 32; off; off >>= 1) ssum += __shfl_xor(ssum, off);
    if (l == 0) red[w] = ssum;
    __syncthreads();

    if (threadIdx.x == 0) {
        float blockSum = red[0] + red[1] + red[2] + red[3];
        int slot = (bid & (NSLOT - 1)) * SLOTSTR;
        __hip_atomic_fetch_add(&slotf[slot], blockSum,
                               __ATOMIC_RELAXED, __HIP_MEMORY_SCOPE_AGENT);
        asm volatile("s_waitcnt vmcnt(0)" ::: "memory");   // order fadd before count
        unsigned o = __hip_atomic_fetch_add(&subcnt[slot], 1u,
                                            __ATOMIC_RELAXED, __HIP_MEMORY_SCOPE_AGENT);
        int last = 0;
        if (o == (PAIRBLK / NSLOT) - 1) {                  // 33rd block of this slot
            unsigned o2 = __hip_atomic_fetch_add(master, 1u,
                                                 __ATOMIC_RELAXED, __HIP_MEMORY_SCOPE_AGENT);
            last = (o2 == NSLOT - 1);
        }
        lastFlag = last;
    }
    __syncthreads();
    if (!lastFlag) return;

    // ---- fused finalize (winner block only; slots coherent via agent atomics,
    //      part_* via kernel-boundary) ----
    double ce = 0.0, fo = 0.0, pr = 0.0;
    int mt = 0;
    for (int i = threadIdx.x; i < ROWBLK; i += 256) {
        float2 v = part_row[i];
        ce += (double)v.x;
        fo += (double)v.y;
        mt += part_match[i];
    }
    for (int i = threadIdx.x; i < NSLOT; i += 256)
        pr += (double)__hip_atomic_load(&slotf[i * SLOTSTR],
                                        __ATOMIC_RELAXED, __HIP_MEMORY_SCOPE_AGENT);

    #pragma unroll
    for (int off = 32; off; off >>= 1) {
        ce += __shfl_xor(ce, off);
        fo += __shfl_xor(fo, off);
        pr += __shfl_xor(pr, off);
        mt += __shfl_xor(mt, off);
    }
    if (l == 0) { lds_ce[w] = ce; lds_fo[w] = fo; lds_pr[w] = pr; lds_mt[w] = mt; }
    __syncthreads();
    if (threadIdx.x == 0) {
        double tce = lds_ce[0] + lds_ce[1] + lds_ce[2] + lds_ce[3];
        double tfo = lds_fo[0] + lds_fo[1] + lds_fo[2] + lds_fo[3];
        double tpr = lds_pr[0] + lds_pr[1] + lds_pr[2] + lds_pr[3];
        int    tmt = lds_mt[0] + lds_mt[1] + lds_mt[2] + lds_mt[3];

        double BN = (double)(BB * NN);
        double loss = (tce / BN) * (tfo / BN);
        double dice = 1.0 - 2.0 * ((double)tmt + 1.0) / (2.0 * BN + 1.0);
        double S = 2.0 * tpr;                    // full matrix sum (diag = 0)
        double mean_pred = S / (BN * (double)NN);
        double dml = 0.05 * log(0.05) - 0.05 * mean_pred;
        out[0] = (float)(loss + dice + dml);
    }
}

extern "C" void kernel_launch(void* const* d_in, const int* in_sizes, int n_in,
                              void* d_out, int out_size, void* d_ws, size_t ws_size,
                              hipStream_t stream)
{
    const float* pred        = (const float*)d_in[0];
    // d_in[1] = y_ohe: unused — the double-where provably collapses dis_map to 0.05
    const int*   targets     = (const int*)d_in[2];
    const int*   pred_choice = (const int*)d_in[3];

    char* ws = (char*)d_ws;
    size_t off = 0;
    unsigned short* p16 = (unsigned short*)ws;               // BB*NN*RP ushorts
    off += (size_t)BB * NN * RP * sizeof(unsigned short);
    float* sqn = (float*)(ws + off);
    off += (size_t)BB * NN * sizeof(float);
    off = (off + 127) & ~(size_t)127;
    float2* part_row = (float2*)(ws + off);                  // ROWBLK float2
    off += (size_t)ROWBLK * sizeof(float2);
    int* part_match = (int*)(ws + off);                      // ROWBLK int
    off += (size_t)ROWBLK * sizeof(int);
    off = (off + 127) & ~(size_t)127;
    float* slotf = (float*)(ws + off);                       // 64 slots x 128 B
    off += (size_t)NSLOT * SLOTSTR * sizeof(float);
    unsigned* subcnt = (unsigned*)(ws + off);                // 64 counters x 128 B
    off += (size_t)NSLOT * SLOTSTR * sizeof(unsigned);
    unsigned* master = (unsigned*)(ws + off);
    off += sizeof(unsigned);

    row_kernel<<<ROWBLK, 512, 0, stream>>>(pred, targets, pred_choice,
                                           p16, sqn, part_row, part_match,
                                           slotf, subcnt, master);
    pair_kernel<<<PAIRBLK, 256, 0, stream>>>(p16, sqn, part_row, part_match,
                                             slotf, subcnt, master, (float*)d_out);
}